// Round 13
// baseline (131.892 us; speedup 1.0000x reference)
//
#include <hip/hip_runtime.h>
#include <hip/hip_bf16.h>

#define B_ 8
#define N_ 8192
#define D_ 512
#define M_ 64

typedef unsigned short u16;
typedef unsigned int u32;
typedef __attribute__((ext_vector_type(8))) short bf16x8;
typedef __attribute__((ext_vector_type(4))) float f32x4;

__device__ __forceinline__ u16 f2bf(float f) {
  u32 u = __float_as_uint(f);
  u += 0x7FFFu + ((u >> 16) & 1u);
  return (u16)(u >> 16);
}
__device__ __forceinline__ float bf2f(u16 h) {
  return __uint_as_float(((u32)h) << 16);
}

// B-fragment index for matrix Mx[kd][c] with N cols: slot mapping shared by A.
__device__ __forceinline__ int bfrag_idx(int kd, int c, int ncols16) {
  int sub = (kd >> 5) * ncols16 + (c >> 4);
  int lane = (c & 15) + 16 * ((kd & 15) >> 2);
  int e = (kd & 3) + 4 * ((kd >> 4) & 1);
  return sub * 512 + lane * 8 + e;
}

// fragment k-slot for (lane, elem) within a 32-k block
__device__ __forceinline__ int kslot(int ln, int e) {
  return (e & 3) + 4 * (ln >> 4) + 16 * (e >> 2);
}

__device__ __forceinline__ bf16x8 pack8(float4 v0, float4 v1) {
  bf16x8 a;
  a[0] = (short)f2bf(v0.x); a[1] = (short)f2bf(v0.y);
  a[2] = (short)f2bf(v0.z); a[3] = (short)f2bf(v0.w);
  a[4] = (short)f2bf(v1.x); a[5] = (short)f2bf(v1.y);
  a[6] = (short)f2bf(v1.z); a[7] = (short)f2bf(v1.w);
  return a;
}

// ---------------------------------------------------------------------------
// k_prep: weights -> bf16 fragment layouts (t2n, n2t, W1 hi/lo, g1, g2)
// ---------------------------------------------------------------------------
__global__ __launch_bounds__(256) void k_prep(
    const float* __restrict__ t2n, const float* __restrict__ n2t,
    const float* __restrict__ W1, const float* __restrict__ g1,
    const float* __restrict__ g2,
    u16* __restrict__ t2nf, u16* __restrict__ n2tf,
    u16* __restrict__ W1h, u16* __restrict__ W1l,
    u16* __restrict__ g1f, u16* __restrict__ g2f)
{
  const int gid = blockIdx.x * 256 + threadIdx.x;
  const int stride = gridDim.x * 256;
  for (int s = gid; s < 512 * 64; s += stride) {
    const int k = s >> 6, c = s & 63;
    const int idx = bfrag_idx(k, c, 4);
    t2nf[idx] = f2bf(t2n[s]);
    const float w = W1[s];
    const u16 wh = f2bf(w);
    W1h[idx] = wh;
    W1l[idx] = f2bf(w - bf2f(wh));
  }
  for (int s = gid; s < 64 * 512; s += stride) {
    const int k = s >> 9, c = s & 511;
    n2tf[bfrag_idx(k, c, 32)] = f2bf(n2t[s]);
  }
  for (int s = gid; s < 4096; s += stride) {
    const int k = s >> 6, c = s & 63;
    g1f[bfrag_idx(k, c, 4)] = f2bf(g1[s]);
    g2f[bfrag_idx(k, c, 4)] = f2bf(g2[s]);
  }
}

// ---------------------------------------------------------------------------
// k_sp: FUSED scores + proj, one X pass, double-buffered LDS B-staging.
// ---------------------------------------------------------------------------
__global__ __launch_bounds__(256, 4) void k_sp(
    const float* __restrict__ X, const u16* __restrict__ W1h,
    const u16* __restrict__ W1l, const u16* __restrict__ t2nf,
    const float* __restrict__ b1, const float* __restrict__ w2,
    const float* __restrict__ b2, float* __restrict__ scores,
    float* __restrict__ outStash)
{
  __shared__ __align__(16) u16 sB[2][6144];  // 2 x 12 frags x 512 u16
  __shared__ __align__(16) u16 sAf[4096];    // proj D->A bounce (post-loop)
  const int tid = threadIdx.x;
  const int t0 = blockIdx.x * 64;
  const int wv = tid >> 6, ln = tid & 63;
  const int lq = ln >> 4, lr = ln & 15;
  u16* mySf = &sAf[wv * 1024];
  const float* xr = X + (size_t)(t0 + 16 * wv + lr) * D_;

  f32x4 acc[4], accP[4];
  #pragma unroll
  for (int cb = 0; cb < 4; ++cb) {
    acc[cb] = (f32x4){0.f, 0.f, 0.f, 0.f};
    accP[cb] = (f32x4){0.f, 0.f, 0.f, 0.f};
  }

  auto gsrc = [&](int f, int kb) -> const u16* {
    const int cb = f / 3, mat = f % 3;
    const u16* mp = (mat == 0) ? W1h : (mat == 1) ? W1l : t2nf;
    return mp + (kb * 4 + cb) * 512 + ln * 8;
  };

  bf16x8 wr[3];
  #pragma unroll
  for (int j = 0; j < 3; ++j)
    *(bf16x8*)&sB[0][(j * 4 + wv) * 512 + ln * 8] = *(const bf16x8*)gsrc(j * 4 + wv, 0);
  #pragma unroll
  for (int j = 0; j < 3; ++j) wr[j] = *(const bf16x8*)gsrc(j * 4 + wv, 1);
  float4 va0 = *(const float4*)(xr + 4 * lq);
  float4 va1 = *(const float4*)(xr + 16 + 4 * lq);
  __syncthreads();

  for (int kb = 0; kb < 16; ++kb) {
    const int cur = kb & 1;
    if (kb < 15) {
      #pragma unroll
      for (int j = 0; j < 3; ++j)
        *(bf16x8*)&sB[cur ^ 1][(j * 4 + wv) * 512 + ln * 8] = wr[j];
    }
    if (kb < 14) {
      #pragma unroll
      for (int j = 0; j < 3; ++j) wr[j] = *(const bf16x8*)gsrc(j * 4 + wv, kb + 2);
    }
    const float4 v0 = va0, v1 = va1;
    if (kb < 15) {
      va0 = *(const float4*)(xr + 32 * (kb + 1) + 4 * lq);
      va1 = *(const float4*)(xr + 32 * (kb + 1) + 16 + 4 * lq);
    }
    const float xs[8] = {v0.x, v0.y, v0.z, v0.w, v1.x, v1.y, v1.z, v1.w};
    bf16x8 ah, al;
    #pragma unroll
    for (int e = 0; e < 8; ++e) {
      const u16 h = f2bf(xs[e]);
      ah[e] = (short)h;
      al[e] = (short)f2bf(xs[e] - bf2f(h));
    }
    #pragma unroll
    for (int cb = 0; cb < 4; ++cb) {
      const bf16x8 bh = *(const bf16x8*)&sB[cur][(cb * 3 + 0) * 512 + ln * 8];
      const bf16x8 bl = *(const bf16x8*)&sB[cur][(cb * 3 + 1) * 512 + ln * 8];
      const bf16x8 bt = *(const bf16x8*)&sB[cur][(cb * 3 + 2) * 512 + ln * 8];
      acc[cb]  = __builtin_amdgcn_mfma_f32_16x16x32_bf16(ah, bh, acc[cb], 0, 0, 0);
      acc[cb]  = __builtin_amdgcn_mfma_f32_16x16x32_bf16(ah, bl, acc[cb], 0, 0, 0);
      acc[cb]  = __builtin_amdgcn_mfma_f32_16x16x32_bf16(al, bh, acc[cb], 0, 0, 0);
      accP[cb] = __builtin_amdgcn_mfma_f32_16x16x32_bf16(ah, bt, accP[cb], 0, 0, 0);
    }
    __syncthreads();
  }

  // ---- scores epilogue
  float b1v[4], w2v[4];
  #pragma unroll
  for (int cb = 0; cb < 4; ++cb) {
    const int col = cb * 16 + lr;
    b1v[cb] = b1[col]; w2v[cb] = w2[col];
  }
  const float b2v = b2[0];
  #pragma unroll
  for (int r = 0; r < 4; ++r) {
    float p = 0.f;
    #pragma unroll
    for (int cb = 0; cb < 4; ++cb) {
      const float h = fmaxf(acc[cb][r] + b1v[cb], 0.f);
      p = fmaf(h, w2v[cb], p);
    }
    p += __shfl_xor(p, 1); p += __shfl_xor(p, 2);
    p += __shfl_xor(p, 4); p += __shfl_xor(p, 8);
    if (lr == 0) scores[t0 + wv * 16 + 4 * lq + r] = p + b2v;
  }

  // ---- proj D->A bounce (wave-private LDS) then coalesced 16B stash
  #pragma unroll
  for (int cb = 0; cb < 4; ++cb)
    #pragma unroll
    for (int r = 0; r < 4; ++r) {
      const int idx = (cb >> 1) * 512 + (4 * lq + r + 16 * (lr >> 2)) * 8 +
                      (lr & 3) + 4 * (cb & 1);
      mySf[idx] = f2bf(accP[cb][r]);
    }
  u16* stash = (u16*)(outStash + (size_t)blockIdx.x * 32768);
  #pragma unroll
  for (int kb2 = 0; kb2 < 2; ++kb2)
    *(bf16x8*)&stash[wv * 1024 + kb2 * 512 + ln * 8] =
        *(const bf16x8*)&mySf[kb2 * 512 + ln * 8];
}

// ---------------------------------------------------------------------------
// k_select: register-resident exact top-64 radix select, 1024 threads.
// Pass-0 histogram uses WAVE-BALLOT AGGREGATION (scores cluster into ~3
// exponent bins -> direct atomics would serialize 8192-way; one atomic per
// distinct bin per wave instead). Passes 1-3: actives spread over ~256 bins,
// direct atomics fine.
// ---------------------------------------------------------------------------
__global__ __launch_bounds__(1024) void k_select(
    const float* __restrict__ scores, int* __restrict__ top_idx,
    int* __restrict__ take_k)
{
  __shared__ u32 hist[256];
  __shared__ float redf[34];
  __shared__ u32 redu[16];
  __shared__ u32 sPrefix, sRank, sCntA, sCntT;
  __shared__ int candIdx[64];
  __shared__ float candVal[64];
  __shared__ int tieIdx[128];
  const int b = blockIdx.x, tid = threadIdx.x;
  const int wv = tid >> 6, ln = tid & 63;
  const float* s = scores + (size_t)b * N_;

  // ---- load 8 elements into registers; stats
  float v[8]; u32 key[8];
  float sum = 0.f, sq = 0.f;
  #pragma unroll
  for (int j = 0; j < 8; ++j) {
    v[j] = s[tid + j * 1024];
    sum += v[j]; sq = fmaf(v[j], v[j], sq);
    const u32 u = __float_as_uint(v[j]);
    key[j] = u ^ ((u32)((int)u >> 31) | 0x80000000u);
  }
  if (tid < 256) hist[tid] = 0;
  #pragma unroll
  for (int off = 32; off > 0; off >>= 1) {
    sum += __shfl_xor(sum, off);
    sq  += __shfl_xor(sq, off);
  }
  if (ln == 0) { redf[wv] = sum; redf[16 + wv] = sq; }
  __syncthreads();
  if (tid < 16) {
    float a = redf[tid], q = redf[16 + tid];
    #pragma unroll
    for (int off = 8; off > 0; off >>= 1) {
      a += __shfl_down(a, off);
      q += __shfl_down(q, off);
    }
    if (tid == 0) {
      const float mean = a / (float)N_;
      const float var = q / (float)N_ - mean * mean;
      redf[32] = mean + 0.5f * sqrtf(fmaxf(var, 0.f));
    }
  }
  __syncthreads();
  const float thr = redf[32];

  // ---- fused: threshold count + pass-0 histogram (ballot-aggregated)
  int c = 0;
  #pragma unroll
  for (int j = 0; j < 8; ++j) {
    c += (v[j] > thr) ? 1 : 0;
    const int bin = (int)(key[j] >> 24);
    unsigned long long act = ~0ull;
    while (act) {
      const int leader = (int)__builtin_ctzll(act);
      const int lbin = __shfl(bin, leader);
      const unsigned long long eq = __ballot(bin == lbin);
      if (ln == leader) atomicAdd(&hist[lbin], (u32)__builtin_popcountll(eq));
      act &= ~eq;
    }
  }
  #pragma unroll
  for (int off = 32; off > 0; off >>= 1) c += __shfl_xor(c, off);
  if (ln == 0) redu[wv] = (u32)c;
  __syncthreads();
  if (tid < 16) {
    u32 a = redu[tid];
    #pragma unroll
    for (int off = 8; off > 0; off >>= 1) a += (u32)__shfl_down((int)a, off);
    if (tid == 0) {
      const int cnt = (int)a;
      take_k[b] = (cnt == 0) ? M_ : (cnt < M_ ? cnt : M_);
    }
  }

  // ---- 4-pass radix: histograms from registers, pick via shfl suffix scan
  u32 prefix = 0, rank = 64, pmask = 0;
  for (int pass = 0; pass < 4; ++pass) {
    const int shift = 24 - 8 * pass;
    if (pass > 0) {
      if (tid < 256) hist[tid] = 0;
      __syncthreads();
      #pragma unroll
      for (int j = 0; j < 8; ++j)
        if ((key[j] & pmask) == prefix) atomicAdd(&hist[(key[j] >> shift) & 255u], 1u);
      __syncthreads();
    }
    if (tid < 64) {
      const u32 h0 = hist[4 * tid], h1 = hist[4 * tid + 1];
      const u32 h2 = hist[4 * tid + 2], h3 = hist[4 * tid + 3];
      const u32 s3 = h3, s2 = h2 + s3, s1 = h1 + s2, s0 = h0 + s1;
      u32 run = s0;
      #pragma unroll
      for (int off = 1; off < 64; off <<= 1) {
        const u32 t = (u32)__shfl_down((int)run, off);
        if (tid + off < 64) run += t;
      }
      const u32 excl = run - s0;
      const u32 c0 = s0 + excl, c1 = s1 + excl, c2 = s2 + excl, c3 = s3 + excl;
      int pick = -1; u32 nxt = 0;
      if (c0 >= rank && c1 < rank)        { pick = 0; nxt = c1; }
      else if (c1 >= rank && c2 < rank)   { pick = 1; nxt = c2; }
      else if (c2 >= rank && c3 < rank)   { pick = 2; nxt = c3; }
      else if (c3 >= rank && excl < rank) { pick = 3; nxt = excl; }
      if (pick >= 0) {
        sPrefix = prefix | ((u32)(4 * tid + pick) << shift);
        sRank = rank - nxt;
      }
    }
    __syncthreads();
    prefix = sPrefix; rank = sRank;
    pmask |= 0xFFu << shift;
    __syncthreads();
  }

  // ---- compaction from registers
  if (tid == 0) { sCntA = 0; sCntT = 0; }
  __syncthreads();
  const u32 pivot = prefix;
  #pragma unroll
  for (int j = 0; j < 8; ++j) {
    if (key[j] > pivot) {
      const u32 p = atomicAdd(&sCntA, 1u);
      candIdx[p] = tid + j * 1024; candVal[p] = v[j];
    } else if (key[j] == pivot) {
      const u32 p = atomicAdd(&sCntT, 1u);
      if (p < 128) tieIdx[p] = tid + j * 1024;
    }
  }
  __syncthreads();
  if (tid == 0) {
    const int nA = (int)sCntA;
    const int need = 64 - nA;
    int nT = (int)sCntT; if (nT > 128) nT = 128;
    const float pv = (pivot & 0x80000000u)
                         ? __uint_as_float(pivot ^ 0x80000000u)
                         : __uint_as_float(~pivot);
    for (int j = 0; j < need; ++j) {
      int bi = 1 << 30, bp = -1;
      for (int q = 0; q < nT; ++q) {
        const int vv = tieIdx[q];
        if (vv >= 0 && vv < bi) { bi = vv; bp = q; }
      }
      candIdx[nA + j] = bi; candVal[nA + j] = pv; tieIdx[bp] = -1;
    }
  }
  __syncthreads();
  if (tid < 64) {
    const float vv = candVal[tid]; const int ii = candIdx[tid];
    int rk = 0;
    for (int j = 0; j < 64; ++j) {
      const float vj = candVal[j]; const int ij = candIdx[j];
      rk += (vj > vv || (vj == vv && ij < ii)) ? 1 : 0;
    }
    top_idx[b * M_ + rk] = ii;
  }
}

// ---------------------------------------------------------------------------
// fragment loaders from fp32 LDS [64][65]
// ---------------------------------------------------------------------------
__device__ __forceinline__ bf16x8 ldsA_frag(const float (*S)[65], int wv, int kb, int ln) {
  const int lr = ln & 15;
  bf16x8 a;
  #pragma unroll
  for (int e = 0; e < 8; ++e) a[e] = (short)f2bf(S[16 * wv + lr][32 * kb + kslot(ln, e)]);
  return a;
}
__device__ __forceinline__ bf16x8 ldsB_frag(const float (*S)[65], int cb, int kb, int ln) {
  const int lr = ln & 15;
  bf16x8 bb;
  #pragma unroll
  for (int e = 0; e < 8; ++e) bb[e] = (short)f2bf(S[32 * kb + kslot(ln, e)][16 * cb + lr]);
  return bb;
}
__device__ __forceinline__ bf16x8 ldsBT_frag(const float (*S)[65], int cb, int kb, int ln) {
  const int lr = ln & 15;
  bf16x8 bb;
  #pragma unroll
  for (int e = 0; e < 8; ++e) bb[e] = (short)f2bf(S[16 * cb + lr][32 * kb + kslot(ln, e)]);
  return bb;
}

// ---------------------------------------------------------------------------
// k_graph: gather + H0 + cosine adjacency + 2-layer GCN + W = Hg@n2t
// ---------------------------------------------------------------------------
__global__ __launch_bounds__(256) void k_graph(
    const float* __restrict__ X, const u16* __restrict__ t2nf,
    const u16* __restrict__ n2tf, const u16* __restrict__ g1f,
    const u16* __restrict__ g2f, const int* __restrict__ top_idx,
    const int* __restrict__ take_k, u16* __restrict__ HgTf,
    u16* __restrict__ Wf)
{
  __shared__ float sH0[64][65];
  __shared__ float sA[64][65];
  __shared__ float sT[64][65];
  __shared__ float sU[64][65];
  __shared__ float sR[64];
  const int b = blockIdx.x, tid = threadIdx.x;
  const int wv = tid >> 6, ln = tid & 63;
  const int lq = ln >> 4, lr = ln & 15;
  const int tk = take_k[b];
  const int rowm = 16 * wv + 4 * lq;

  const int gidx = top_idx[b * M_ + 16 * wv + lr];
  const float* xr = X + ((size_t)b * N_ + gidx) * D_;
  f32x4 d[4];
  #pragma unroll
  for (int cb = 0; cb < 4; ++cb) d[cb] = (f32x4){0.f, 0.f, 0.f, 0.f};
  {
    float4 p0[3], p1[3];
    #pragma unroll
    for (int q = 0; q < 3; ++q) {
      p0[q] = *(const float4*)(xr + 32 * q + 4 * lq);
      p1[q] = *(const float4*)(xr + 32 * q + 16 + 4 * lq);
    }
    #pragma unroll
    for (int kb = 0; kb < 16; ++kb) {
      const int slot = kb % 3;
      const float4 v0 = p0[slot], v1 = p1[slot];
      if (kb + 3 < 16) {
        p0[slot] = *(const float4*)(xr + 32 * (kb + 3) + 4 * lq);
        p1[slot] = *(const float4*)(xr + 32 * (kb + 3) + 16 + 4 * lq);
      }
      const bf16x8 a = pack8(v0, v1);
      #pragma unroll
      for (int cb = 0; cb < 4; ++cb) {
        const bf16x8 bb = *(const bf16x8*)&t2nf[(kb * 4 + cb) * 512 + ln * 8];
        d[cb] = __builtin_amdgcn_mfma_f32_16x16x32_bf16(a, bb, d[cb], 0, 0, 0);
      }
    }
  }
  #pragma unroll
  for (int cb = 0; cb < 4; ++cb)
    #pragma unroll
    for (int r = 0; r < 4; ++r)
      sH0[rowm + r][16 * cb + lr] = (rowm + r < tk) ? d[cb][r] : 0.f;
  __syncthreads();

  if (tid < 64) {
    float ss = 0.f;
    #pragma unroll
    for (int k = 0; k < 64; ++k) { const float vv = sH0[tid][k]; ss = fmaf(vv, vv, ss); }
    sR[tid] = 1.f / fmaxf(sqrtf(ss), 1e-6f);
  }
  __syncthreads();
  #pragma unroll
  for (int p = 0; p < 16; ++p) {
    const int o = tid + p * 256;
    sU[o >> 6][o & 63] = sH0[o >> 6][o & 63] * sR[o >> 6];
  }
  __syncthreads();

  #pragma unroll
  for (int cb = 0; cb < 4; ++cb) d[cb] = (f32x4){0.f, 0.f, 0.f, 0.f};
  #pragma unroll
  for (int kb = 0; kb < 2; ++kb) {
    const bf16x8 a = ldsA_frag(sU, wv, kb, ln);
    #pragma unroll
    for (int cb = 0; cb < 4; ++cb)
      d[cb] = __builtin_amdgcn_mfma_f32_16x16x32_bf16(a, ldsBT_frag(sU, cb, kb, ln), d[cb], 0, 0, 0);
  }
  __syncthreads();
  #pragma unroll
  for (int cb = 0; cb < 4; ++cb)
    #pragma unroll
    for (int r = 0; r < 4; ++r) {
      const int row = rowm + r, col = 16 * cb + lr;
      float ss = fmaxf(d[cb][r], 0.f);
      ss = (row < tk && col < tk) ? ss : 0.f;
      if (row == col && row < tk) ss += 1.f;
      sA[row][col] = ss;
    }
  __syncthreads();

  if (tid < 64) {
    float rs = 0.f;
    #pragma unroll
    for (int j = 0; j < 64; ++j) rs += sA[tid][j];
    sR[tid] = 1.f / fmaxf(rs, 1e-6f);
  }
  __syncthreads();
  #pragma unroll
  for (int p = 0; p < 16; ++p) {
    const int o = tid + p * 256;
    sA[o >> 6][o & 63] *= sR[o >> 6];
  }
  __syncthreads();

  #pragma unroll
  for (int cb = 0; cb < 4; ++cb) d[cb] = (f32x4){0.f, 0.f, 0.f, 0.f};
  #pragma unroll
  for (int kb = 0; kb < 2; ++kb) {
    const bf16x8 a = ldsA_frag(sA, wv, kb, ln);
    #pragma unroll
    for (int cb = 0; cb < 4; ++cb)
      d[cb] = __builtin_amdgcn_mfma_f32_16x16x32_bf16(a, ldsB_frag(sH0, cb, kb, ln), d[cb], 0, 0, 0);
  }
  __syncthreads();
  #pragma unroll
  for (int cb = 0; cb < 4; ++cb)
    #pragma unroll
    for (int r = 0; r < 4; ++r) sT[rowm + r][16 * cb + lr] = d[cb][r];
  __syncthreads();

  #pragma unroll
  for (int cb = 0; cb < 4; ++cb) d[cb] = (f32x4){0.f, 0.f, 0.f, 0.f};
  #pragma unroll
  for (int kb = 0; kb < 2; ++kb) {
    const bf16x8 a = ldsA_frag(sT, wv, kb, ln);
    #pragma unroll
    for (int cb = 0; cb < 4; ++cb) {
      const bf16x8 bb = *(const bf16x8*)&g1f[(kb * 4 + cb) * 512 + ln * 8];
      d[cb] = __builtin_amdgcn_mfma_f32_16x16x32_bf16(a, bb, d[cb], 0, 0, 0);
    }
  }
  __syncthreads();
  #pragma unroll
  for (int cb = 0; cb < 4; ++cb)
    #pragma unroll
    for (int r = 0; r < 4; ++r) sU[rowm + r][16 * cb + lr] = fmaxf(d[cb][r], 0.f);
  __syncthreads();

  #pragma unroll
  for (int cb = 0; cb < 4; ++cb) d[cb] = (f32x4){0.f, 0.f, 0.f, 0.f};
  #pragma unroll
  for (int kb = 0; kb < 2; ++kb) {
    const bf16x8 a = ldsA_frag(sA, wv, kb, ln);
    #pragma unroll
    for (int cb = 0; cb < 4; ++cb)
      d[cb] = __builtin_amdgcn_mfma_f32_16x16x32_bf16(a, ldsB_frag(sU, cb, kb, ln), d[cb], 0, 0, 0);
  }
  __syncthreads();
  #pragma unroll
  for (int cb = 0; cb < 4; ++cb)
    #pragma unroll
    for (int r = 0; r < 4; ++r) sT[rowm + r][16 * cb + lr] = d[cb][r];
  __syncthreads();

  #pragma unroll
  for (int cb = 0; cb < 4; ++cb) d[cb] = (f32x4){0.f, 0.f, 0.f, 0.f};
  #pragma unroll
  for (int kb = 0; kb < 2; ++kb) {
    const bf16x8 a = ldsA_frag(sT, wv, kb, ln);
    #pragma unroll
    for (int cb = 0; cb < 4; ++cb) {
      const bf16x8 bb = *(const bf16x8*)&g2f[(kb * 4 + cb) * 512 + ln * 8];
      d[cb] = __builtin_amdgcn_mfma_f32_16x16x32_bf16(a, bb, d[cb], 0, 0, 0);
    }
  }
  __syncthreads();
  #pragma unroll
  for (int cb = 0; cb < 4; ++cb)
    #pragma unroll
    for (int r = 0; r < 4; ++r) {
      const int node = rowm + r, feat = 16 * cb + lr;
      const float hv = fmaxf(d[cb][r], 0.f);
      HgTf[(size_t)b * 4096 + bfrag_idx(feat, node, 4)] = f2bf(hv);
      sU[node][feat] = hv;
    }
  __syncthreads();

  for (int chk = 0; chk < 4; ++chk) {
    f32x4 aw[8];
    #pragma unroll
    for (int c8 = 0; c8 < 8; ++c8) aw[c8] = (f32x4){0.f, 0.f, 0.f, 0.f};
    #pragma unroll
    for (int kbf = 0; kbf < 2; ++kbf) {
      const bf16x8 a = ldsA_frag(sU, wv, kbf, ln);
      #pragma unroll
      for (int c8 = 0; c8 < 8; ++c8) {
        const bf16x8 bb = *(const bf16x8*)&n2tf[(kbf * 32 + chk * 8 + c8) * 512 + ln * 8];
        aw[c8] = __builtin_amdgcn_mfma_f32_16x16x32_bf16(a, bb, aw[c8], 0, 0, 0);
      }
    }
    #pragma unroll
    for (int c8 = 0; c8 < 8; ++c8)
      #pragma unroll
      for (int r = 0; r < 4; ++r) {
        const int m = 16 * wv + 4 * lq + r;
        const int cc = (chk * 8 + c8) * 16 + lr;
        Wf[(size_t)b * 32768 + bfrag_idx(m, cc, 32)] = f2bf(aw[c8][r]);
      }
  }
}

// ---------------------------------------------------------------------------
// k_attn: logits(stash)->softmax->back(attn@W)+residual, float4 epilogue
// ---------------------------------------------------------------------------
__global__ __launch_bounds__(256) void k_attn(
    const float* __restrict__ X, const u16* __restrict__ HgTf,
    const u16* __restrict__ Wf, float* __restrict__ out)
{
  __shared__ __align__(16) u16 sAf[4096];
  __shared__ __align__(16) float sBo[4][16][68];
  const int tid = threadIdx.x;
  const int b = blockIdx.x >> 7;
  const int t0 = (blockIdx.x & 127) << 6;
  const float* Xb = X + (size_t)b * N_ * D_;
  float* Ob = out + (size_t)b * N_ * D_;
  const int wv = tid >> 6, ln = tid & 63;
  const int lq = ln >> 4, lr = ln & 15;
  u16* mySf = &sAf[wv * 1024];
  const u16* stash = (const u16*)(out + (size_t)blockIdx.x * 32768);

  f32x4 accL[4];
  #pragma unroll
  for (int cb = 0; cb < 4; ++cb) accL[cb] = (f32x4){0.f, 0.f, 0.f, 0.f};
  #pragma unroll
  for (int kb = 0; kb < 2; ++kb) {
    const bf16x8 a = *(const bf16x8*)&stash[wv * 1024 + kb * 512 + ln * 8];
    #pragma unroll
    for (int cb = 0; cb < 4; ++cb) {
      const bf16x8 bb = *(const bf16x8*)&HgTf[(size_t)b * 4096 + (kb * 4 + cb) * 512 + ln * 8];
      accL[cb] = __builtin_amdgcn_mfma_f32_16x16x32_bf16(a, bb, accL[cb], 0, 0, 0);
    }
  }
  __syncthreads();

  float attnv[4][4];
  #pragma unroll
  for (int r = 0; r < 4; ++r) {
    const float v0 = accL[0][r], v1 = accL[1][r], v2 = accL[2][r], v3 = accL[3][r];
    float mx = fmaxf(fmaxf(v0, v1), fmaxf(v2, v3));
    mx = fmaxf(mx, __shfl_xor(mx, 1)); mx = fmaxf(mx, __shfl_xor(mx, 2));
    mx = fmaxf(mx, __shfl_xor(mx, 4)); mx = fmaxf(mx, __shfl_xor(mx, 8));
    const float e0 = __expf((v0 - mx) * 0.125f), e1 = __expf((v1 - mx) * 0.125f);
    const float e2 = __expf((v2 - mx) * 0.125f), e3 = __expf((v3 - mx) * 0.125f);
    float sm = (e0 + e1) + (e2 + e3);
    sm += __shfl_xor(sm, 1); sm += __shfl_xor(sm, 2);
    sm += __shfl_xor(sm, 4); sm += __shfl_xor(sm, 8);
    const float inv = 1.f / sm;
    attnv[0][r] = e0 * inv; attnv[1][r] = e1 * inv;
    attnv[2][r] = e2 * inv; attnv[3][r] = e3 * inv;
  }
  #pragma unroll
  for (int cb = 0; cb < 4; ++cb)
    #pragma unroll
    for (int r = 0; r < 4; ++r) {
      const int idx = (cb >> 1) * 512 + (4 * lq + r + 16 * (lr >> 2)) * 8 +
                      (lr & 3) + 4 * (cb & 1);
      mySf[idx] = f2bf(attnv[cb][r]);
    }

  for (int chk = 0; chk < 4; ++chk) {
    float4 xres[8];
    #pragma unroll
    for (int h = 0; h < 2; ++h)
      #pragma unroll
      for (int j = 0; j < 4; ++j)
        xres[h * 4 + j] = *(const float4*)(
            Xb + (size_t)(t0 + 16 * wv + 4 * j + lq) * D_ + chk * 128 + h * 64 + 4 * lr);

    f32x4 accB[8];
    #pragma unroll
    for (int c8 = 0; c8 < 8; ++c8) accB[c8] = (f32x4){0.f, 0.f, 0.f, 0.f};
    #pragma unroll
    for (int kb = 0; kb < 2; ++kb) {
      const bf16x8 a = *(const bf16x8*)&mySf[kb * 512 + ln * 8];
      #pragma unroll
      for (int c8 = 0; c8 < 8; ++c8) {
        const bf16x8 bb = *(const bf16x8*)&Wf[(size_t)b * 32768 + (kb * 32 + chk * 8 + c8) * 512 + ln * 8];
        accB[c8] = __builtin_amdgcn_mfma_f32_16x16x32_bf16(a, bb, accB[c8], 0, 0, 0);
      }
    }
    #pragma unroll
    for (int h = 0; h < 2; ++h) {
      #pragma unroll
      for (int c4 = 0; c4 < 4; ++c4)
        #pragma unroll
        for (int r = 0; r < 4; ++r)
          sBo[wv][4 * lq + r][c4 * 16 + lr] = accB[4 * h + c4][r];
      #pragma unroll
      for (int j = 0; j < 4; ++j) {
        const int rloc = 4 * j + lq;
        float4 vv = *(const float4*)&sBo[wv][rloc][4 * lr];
        const float4 xv = xres[h * 4 + j];
        vv.x += xv.x; vv.y += xv.y; vv.z += xv.z; vv.w += xv.w;
        *(float4*)(Ob + (size_t)(t0 + 16 * wv + rloc) * D_ + chk * 128 + h * 64 + 4 * lr) = vv;
      }
    }
  }
}

// ---------------------------------------------------------------------------
extern "C" void kernel_launch(void* const* d_in, const int* in_sizes, int n_in,
                              void* d_out, int out_size, void* d_ws, size_t ws_size,
                              hipStream_t stream)
{
  (void)in_sizes; (void)n_in; (void)out_size; (void)ws_size;
  const float* X   = (const float*)d_in[0];
  const float* W1  = (const float*)d_in[1];
  const float* b1  = (const float*)d_in[2];
  const float* w2  = (const float*)d_in[3];
  const float* b2  = (const float*)d_in[4];
  const float* t2n = (const float*)d_in[5];
  const float* n2t = (const float*)d_in[6];
  const float* g1  = (const float*)d_in[7];
  const float* g2  = (const float*)d_in[8];
  float* out = (float*)d_out;

  char* ws = (char*)d_ws;
  float* scores = (float*)(ws);                  // 256 KB
  u16* t2nf     = (u16*)(ws + 262144);           // 64 KB
  u16* n2tf     = (u16*)(ws + 327680);           // 64 KB
  u16* W1h      = (u16*)(ws + 393216);           // 64 KB
  u16* W1l      = (u16*)(ws + 458752);           // 64 KB
  u16* HgTf     = (u16*)(ws + 524288);           // 64 KB
  u16* g1f      = (u16*)(ws + 589824);           // 8 KB
  u16* g2f      = (u16*)(ws + 598016);           // 8 KB
  int* top_idx  = (int*)(ws + 606208);           // 2 KB
  int* take_k   = (int*)(ws + 608256);           // 32 B
  u16* Wf       = (u16*)(ws + 609280);           // 512 KB

  k_prep<<<64, 256, 0, stream>>>(t2n, n2t, W1, g1, g2, t2nf, n2tf, W1h, W1l, g1f, g2f);
  k_sp<<<1024, 256, 0, stream>>>(X, W1h, W1l, t2nf, b1, w2, b2, scores, out);
  k_select<<<B_, 1024, 0, stream>>>(scores, top_idx, take_k);
  k_graph<<<B_, 256, 0, stream>>>(X, t2nf, n2tf, g1f, g2f, top_idx, take_k, HgTf, Wf);
  k_attn<<<1024, 256, 0, stream>>>(X, HgTf, Wf, out);
}

// Round 14
// 123.185 us; speedup vs baseline: 1.0707x; 1.0707x over previous
//
#include <hip/hip_runtime.h>
#include <hip/hip_bf16.h>

#define B_ 8
#define N_ 8192
#define D_ 512
#define M_ 64

typedef unsigned short u16;
typedef unsigned int u32;
typedef __attribute__((ext_vector_type(8))) short bf16x8;
typedef __attribute__((ext_vector_type(4))) float f32x4;

__device__ __forceinline__ u16 f2bf(float f) {
  u32 u = __float_as_uint(f);
  u += 0x7FFFu + ((u >> 16) & 1u);
  return (u16)(u >> 16);
}
__device__ __forceinline__ float bf2f(u16 h) {
  return __uint_as_float(((u32)h) << 16);
}

// B-fragment index for matrix Mx[kd][c] with N cols: slot mapping shared by A.
__device__ __forceinline__ int bfrag_idx(int kd, int c, int ncols16) {
  int sub = (kd >> 5) * ncols16 + (c >> 4);
  int lane = (c & 15) + 16 * ((kd & 15) >> 2);
  int e = (kd & 3) + 4 * ((kd >> 4) & 1);
  return sub * 512 + lane * 8 + e;
}

// fragment k-slot for (lane, elem) within a 32-k block
__device__ __forceinline__ int kslot(int ln, int e) {
  return (e & 3) + 4 * (ln >> 4) + 16 * (e >> 2);
}

__device__ __forceinline__ bf16x8 pack8(float4 v0, float4 v1) {
  bf16x8 a;
  a[0] = (short)f2bf(v0.x); a[1] = (short)f2bf(v0.y);
  a[2] = (short)f2bf(v0.z); a[3] = (short)f2bf(v0.w);
  a[4] = (short)f2bf(v1.x); a[5] = (short)f2bf(v1.y);
  a[6] = (short)f2bf(v1.z); a[7] = (short)f2bf(v1.w);
  return a;
}

// ---------------------------------------------------------------------------
// k_prep: weights -> bf16 fragment layouts (t2n, n2t, W1 hi/lo, g1, g2)
// ---------------------------------------------------------------------------
__global__ __launch_bounds__(256) void k_prep(
    const float* __restrict__ t2n, const float* __restrict__ n2t,
    const float* __restrict__ W1, const float* __restrict__ g1,
    const float* __restrict__ g2,
    u16* __restrict__ t2nf, u16* __restrict__ n2tf,
    u16* __restrict__ W1h, u16* __restrict__ W1l,
    u16* __restrict__ g1f, u16* __restrict__ g2f)
{
  const int gid = blockIdx.x * 256 + threadIdx.x;
  const int stride = gridDim.x * 256;
  for (int s = gid; s < 512 * 64; s += stride) {
    const int k = s >> 6, c = s & 63;
    const int idx = bfrag_idx(k, c, 4);
    t2nf[idx] = f2bf(t2n[s]);
    const float w = W1[s];
    const u16 wh = f2bf(w);
    W1h[idx] = wh;
    W1l[idx] = f2bf(w - bf2f(wh));
  }
  for (int s = gid; s < 64 * 512; s += stride) {
    const int k = s >> 9, c = s & 511;
    n2tf[bfrag_idx(k, c, 32)] = f2bf(n2t[s]);
  }
  for (int s = gid; s < 4096; s += stride) {
    const int k = s >> 6, c = s & 63;
    g1f[bfrag_idx(k, c, 4)] = f2bf(g1[s]);
    g2f[bfrag_idx(k, c, 4)] = f2bf(g2[s]);
  }
}

// ---------------------------------------------------------------------------
// k_sp: FUSED scores + proj, one X pass, double-buffered LDS B-staging.
// ---------------------------------------------------------------------------
__global__ __launch_bounds__(256, 4) void k_sp(
    const float* __restrict__ X, const u16* __restrict__ W1h,
    const u16* __restrict__ W1l, const u16* __restrict__ t2nf,
    const float* __restrict__ b1, const float* __restrict__ w2,
    const float* __restrict__ b2, float* __restrict__ scores,
    float* __restrict__ outStash)
{
  __shared__ __align__(16) u16 sB[2][6144];  // 2 x 12 frags x 512 u16
  __shared__ __align__(16) u16 sAf[4096];    // proj D->A bounce (post-loop)
  const int tid = threadIdx.x;
  const int t0 = blockIdx.x * 64;
  const int wv = tid >> 6, ln = tid & 63;
  const int lq = ln >> 4, lr = ln & 15;
  u16* mySf = &sAf[wv * 1024];
  const float* xr = X + (size_t)(t0 + 16 * wv + lr) * D_;

  f32x4 acc[4], accP[4];
  #pragma unroll
  for (int cb = 0; cb < 4; ++cb) {
    acc[cb] = (f32x4){0.f, 0.f, 0.f, 0.f};
    accP[cb] = (f32x4){0.f, 0.f, 0.f, 0.f};
  }

  auto gsrc = [&](int f, int kb) -> const u16* {
    const int cb = f / 3, mat = f % 3;
    const u16* mp = (mat == 0) ? W1h : (mat == 1) ? W1l : t2nf;
    return mp + (kb * 4 + cb) * 512 + ln * 8;
  };

  bf16x8 wr[3];
  #pragma unroll
  for (int j = 0; j < 3; ++j)
    *(bf16x8*)&sB[0][(j * 4 + wv) * 512 + ln * 8] = *(const bf16x8*)gsrc(j * 4 + wv, 0);
  #pragma unroll
  for (int j = 0; j < 3; ++j) wr[j] = *(const bf16x8*)gsrc(j * 4 + wv, 1);
  float4 va0 = *(const float4*)(xr + 4 * lq);
  float4 va1 = *(const float4*)(xr + 16 + 4 * lq);
  __syncthreads();

  for (int kb = 0; kb < 16; ++kb) {
    const int cur = kb & 1;
    if (kb < 15) {
      #pragma unroll
      for (int j = 0; j < 3; ++j)
        *(bf16x8*)&sB[cur ^ 1][(j * 4 + wv) * 512 + ln * 8] = wr[j];
    }
    if (kb < 14) {
      #pragma unroll
      for (int j = 0; j < 3; ++j) wr[j] = *(const bf16x8*)gsrc(j * 4 + wv, kb + 2);
    }
    const float4 v0 = va0, v1 = va1;
    if (kb < 15) {
      va0 = *(const float4*)(xr + 32 * (kb + 1) + 4 * lq);
      va1 = *(const float4*)(xr + 32 * (kb + 1) + 16 + 4 * lq);
    }
    const float xs[8] = {v0.x, v0.y, v0.z, v0.w, v1.x, v1.y, v1.z, v1.w};
    bf16x8 ah, al;
    #pragma unroll
    for (int e = 0; e < 8; ++e) {
      const u16 h = f2bf(xs[e]);
      ah[e] = (short)h;
      al[e] = (short)f2bf(xs[e] - bf2f(h));
    }
    #pragma unroll
    for (int cb = 0; cb < 4; ++cb) {
      const bf16x8 bh = *(const bf16x8*)&sB[cur][(cb * 3 + 0) * 512 + ln * 8];
      const bf16x8 bl = *(const bf16x8*)&sB[cur][(cb * 3 + 1) * 512 + ln * 8];
      const bf16x8 bt = *(const bf16x8*)&sB[cur][(cb * 3 + 2) * 512 + ln * 8];
      acc[cb]  = __builtin_amdgcn_mfma_f32_16x16x32_bf16(ah, bh, acc[cb], 0, 0, 0);
      acc[cb]  = __builtin_amdgcn_mfma_f32_16x16x32_bf16(ah, bl, acc[cb], 0, 0, 0);
      acc[cb]  = __builtin_amdgcn_mfma_f32_16x16x32_bf16(al, bh, acc[cb], 0, 0, 0);
      accP[cb] = __builtin_amdgcn_mfma_f32_16x16x32_bf16(ah, bt, accP[cb], 0, 0, 0);
    }
    __syncthreads();
  }

  // ---- scores epilogue
  float b1v[4], w2v[4];
  #pragma unroll
  for (int cb = 0; cb < 4; ++cb) {
    const int col = cb * 16 + lr;
    b1v[cb] = b1[col]; w2v[cb] = w2[col];
  }
  const float b2v = b2[0];
  #pragma unroll
  for (int r = 0; r < 4; ++r) {
    float p = 0.f;
    #pragma unroll
    for (int cb = 0; cb < 4; ++cb) {
      const float h = fmaxf(acc[cb][r] + b1v[cb], 0.f);
      p = fmaf(h, w2v[cb], p);
    }
    p += __shfl_xor(p, 1); p += __shfl_xor(p, 2);
    p += __shfl_xor(p, 4); p += __shfl_xor(p, 8);
    if (lr == 0) scores[t0 + wv * 16 + 4 * lq + r] = p + b2v;
  }

  // ---- proj D->A bounce (wave-private LDS) then coalesced 16B stash
  #pragma unroll
  for (int cb = 0; cb < 4; ++cb)
    #pragma unroll
    for (int r = 0; r < 4; ++r) {
      const int idx = (cb >> 1) * 512 + (4 * lq + r + 16 * (lr >> 2)) * 8 +
                      (lr & 3) + 4 * (cb & 1);
      mySf[idx] = f2bf(accP[cb][r]);
    }
  u16* stash = (u16*)(outStash + (size_t)blockIdx.x * 32768);
  #pragma unroll
  for (int kb2 = 0; kb2 < 2; ++kb2)
    *(bf16x8*)&stash[wv * 1024 + kb2 * 512 + ln * 8] =
        *(const bf16x8*)&mySf[kb2 * 512 + ln * 8];
}

// ---------------------------------------------------------------------------
// k_select: exact top-64 via ONE 2048-bin (11-bit) histogram + suffix scan +
// parallel tie ranking. Register-resident; ~6 barriers; no serial loops.
// ---------------------------------------------------------------------------
__global__ __launch_bounds__(1024) void k_select(
    const float* __restrict__ scores, int* __restrict__ top_idx,
    int* __restrict__ take_k)
{
  __shared__ u32 hist[2048];
  __shared__ float redf[34];
  __shared__ u32 redu[16];
  __shared__ u32 scanp[16];
  __shared__ int sPivotBin;
  __shared__ u32 sTake, sNA, sCntA, sCntT;
  __shared__ int candIdx[64];
  __shared__ u32 candKey[64];
  __shared__ int tieIdx[1024];
  __shared__ u32 tieKey[1024];
  const int b = blockIdx.x, tid = threadIdx.x;
  const int wv = tid >> 6, ln = tid & 63;
  const float* s = scores + (size_t)b * N_;

  hist[tid] = 0; hist[tid + 1024] = 0;
  if (tid == 0) { sCntA = 0; sCntT = 0; }

  // ---- load 8 elements into registers; monotone keys; stats partials
  float v[8]; u32 key[8];
  float sum = 0.f, sq = 0.f;
  #pragma unroll
  for (int j = 0; j < 8; ++j) {
    v[j] = s[tid + j * 1024];
    sum += v[j]; sq = fmaf(v[j], v[j], sq);
    const u32 u = __float_as_uint(v[j]);
    key[j] = u ^ ((u32)((int)u >> 31) | 0x80000000u);
  }
  #pragma unroll
  for (int off = 32; off > 0; off >>= 1) {
    sum += __shfl_xor(sum, off);
    sq  += __shfl_xor(sq, off);
  }
  if (ln == 0) { redf[wv] = sum; redf[16 + wv] = sq; }
  __syncthreads();  // B1: hist zeroed, stat partials written

  // ---- histogram (2048 bins -> low contention, direct atomics)
  #pragma unroll
  for (int j = 0; j < 8; ++j) atomicAdd(&hist[key[j] >> 21], 1u);
  // ---- threshold from stats (independent of hist)
  if (tid < 16) {
    float a = redf[tid], q = redf[16 + tid];
    #pragma unroll
    for (int off = 8; off > 0; off >>= 1) {
      a += __shfl_down(a, off);
      q += __shfl_down(q, off);
    }
    if (tid == 0) {
      const float mean = a / (float)N_;
      const float var = q / (float)N_ - mean * mean;
      redf[32] = mean + 0.5f * sqrtf(fmaxf(var, 0.f));
    }
  }
  __syncthreads();  // B2: hist complete, thr ready
  const float thr = redf[32];

  // ---- count (> thr) from registers
  int c = 0;
  #pragma unroll
  for (int j = 0; j < 8; ++j) c += (v[j] > thr) ? 1 : 0;
  #pragma unroll
  for (int off = 32; off > 0; off >>= 1) c += __shfl_xor(c, off);
  if (ln == 0) redu[wv] = (u32)c;

  // ---- suffix scan over bin pairs (thread t owns bins 2t, 2t+1)
  const u32 h_hi = hist[2 * tid], h_lo = hist[2 * tid + 1];
  const u32 ps = h_hi + h_lo;
  u32 run = ps;
  #pragma unroll
  for (int off = 1; off < 64; off <<= 1) {
    const u32 t = (u32)__shfl((int)run, ln + off);
    if (ln + off < 64) run += t;
  }
  if (ln == 0) scanp[wv] = run;  // wave total
  __syncthreads();  // B3: redu + scanp written

  if (tid < 16) {
    u32 a = redu[tid];
    #pragma unroll
    for (int off = 8; off > 0; off >>= 1) a += (u32)__shfl_down((int)a, off);
    if (tid == 0) {
      const int cnt = (int)a;
      take_k[b] = (cnt == 0) ? M_ : (cnt < M_ ? cnt : M_);
    }
  }
  {
    u32 ws = 0;
    for (int w = wv + 1; w < 16; ++w) ws += scanp[w];
    const u32 suffIncl = run + ws;             // cumGE(bin 2*tid)
    const u32 cumMid = suffIncl - h_hi;        // cumGE(bin 2*tid+1)
    const u32 cumNext = suffIncl - ps;         // cumGE(bin 2*tid+2)
    if (suffIncl >= 64u && cumMid < 64u) {
      sPivotBin = 2 * tid; sTake = 64u - cumMid; sNA = cumMid;
    }
    if (cumMid >= 64u && cumNext < 64u) {
      sPivotBin = 2 * tid + 1; sTake = 64u - cumNext; sNA = cumNext;
    }
  }
  __syncthreads();  // B4: pivot known

  // ---- compact above/tie candidates from registers
  const int pb = sPivotBin;
  #pragma unroll
  for (int j = 0; j < 8; ++j) {
    const int bin = (int)(key[j] >> 21);
    if (bin > pb) {
      const u32 p = atomicAdd(&sCntA, 1u);
      candIdx[p] = tid + j * 1024; candKey[p] = key[j];
    } else if (bin == pb) {
      const u32 p = atomicAdd(&sCntT, 1u);
      if (p < 1024u) { tieIdx[p] = tid + j * 1024; tieKey[p] = key[j]; }
    }
  }
  __syncthreads();  // B5: candidates compacted

  // ---- parallel tie ranking: select top (64-nA) ties by (key desc, idx asc)
  const int nA = (int)sNA;
  const int need = (int)sTake;
  const int T = (int)(sCntT < 1024u ? sCntT : 1024u);
  for (int t = tid; t < T; t += 1024) {
    const u32 k0 = tieKey[t]; const int i0 = tieIdx[t];
    int rk = 0;
    for (int q = 0; q < T; ++q) {
      const u32 kq = tieKey[q]; const int iq = tieIdx[q];
      rk += (kq > k0 || (kq == k0 && iq < i0)) ? 1 : 0;
    }
    if (rk < need) { candIdx[nA + rk] = i0; candKey[nA + rk] = k0; }
  }
  __syncthreads();  // B6: 64 candidates final

  // ---- rank-order the 64 winners by (key desc, idx asc)
  if (tid < 64) {
    const u32 k0 = candKey[tid]; const int i0 = candIdx[tid];
    int rk = 0;
    for (int q = 0; q < 64; ++q) {
      const u32 kq = candKey[q]; const int iq = candIdx[q];
      rk += (kq > k0 || (kq == k0 && iq < i0)) ? 1 : 0;
    }
    top_idx[b * M_ + rk] = i0;
  }
}

// ---------------------------------------------------------------------------
// fragment loaders from fp32 LDS [64][65]  (g = row-group 0..3)
// ---------------------------------------------------------------------------
__device__ __forceinline__ bf16x8 ldsA_frag(const float (*S)[65], int g, int kb, int ln) {
  const int lr = ln & 15;
  bf16x8 a;
  #pragma unroll
  for (int e = 0; e < 8; ++e) a[e] = (short)f2bf(S[16 * g + lr][32 * kb + kslot(ln, e)]);
  return a;
}
__device__ __forceinline__ bf16x8 ldsB_frag(const float (*S)[65], int cb, int kb, int ln) {
  const int lr = ln & 15;
  bf16x8 bb;
  #pragma unroll
  for (int e = 0; e < 8; ++e) bb[e] = (short)f2bf(S[32 * kb + kslot(ln, e)][16 * cb + lr]);
  return bb;
}
__device__ __forceinline__ bf16x8 ldsBT_frag(const float (*S)[65], int cb, int kb, int ln) {
  const int lr = ln & 15;
  bf16x8 bb;
  #pragma unroll
  for (int e = 0; e < 8; ++e) bb[e] = (short)f2bf(S[16 * cb + lr][32 * kb + kslot(ln, e)]);
  return bb;
}

// ---------------------------------------------------------------------------
// k_graph (512 threads): gather + H0 + adjacency + 2-layer GCN + W = Hg@n2t.
// 8 waves: row-group g = wv&3, column-half hh = wv>>2 (2 cb each) -> every
// matmul phase's critical path halves vs the 256-thread version.
// ---------------------------------------------------------------------------
__global__ __launch_bounds__(512) void k_graph(
    const float* __restrict__ X, const u16* __restrict__ t2nf,
    const u16* __restrict__ n2tf, const u16* __restrict__ g1f,
    const u16* __restrict__ g2f, const int* __restrict__ top_idx,
    const int* __restrict__ take_k, u16* __restrict__ HgTf,
    u16* __restrict__ Wf)
{
  __shared__ float sH0[64][65];
  __shared__ float sA[64][65];
  __shared__ float sT[64][65];
  __shared__ float sU[64][65];
  __shared__ float sR[64];
  const int b = blockIdx.x, tid = threadIdx.x;
  const int wv = tid >> 6, ln = tid & 63;
  const int lq = ln >> 4, lr = ln & 15;
  const int g = wv & 3;    // row group
  const int hh = wv >> 2;  // cb half
  const int tk = take_k[b];
  const int rowm = 16 * g + 4 * lq;

  // ---- H0 = gather(X) @ t2n (K=512), masked; depth-3 prefetch ring
  const int gidx = top_idx[b * M_ + 16 * g + lr];
  const float* xr = X + ((size_t)b * N_ + gidx) * D_;
  f32x4 d[2];
  #pragma unroll
  for (int cc = 0; cc < 2; ++cc) d[cc] = (f32x4){0.f, 0.f, 0.f, 0.f};
  {
    float4 p0[3], p1[3];
    #pragma unroll
    for (int q = 0; q < 3; ++q) {
      p0[q] = *(const float4*)(xr + 32 * q + 4 * lq);
      p1[q] = *(const float4*)(xr + 32 * q + 16 + 4 * lq);
    }
    #pragma unroll
    for (int kb = 0; kb < 16; ++kb) {
      const int slot = kb % 3;
      const float4 v0 = p0[slot], v1 = p1[slot];
      if (kb + 3 < 16) {
        p0[slot] = *(const float4*)(xr + 32 * (kb + 3) + 4 * lq);
        p1[slot] = *(const float4*)(xr + 32 * (kb + 3) + 16 + 4 * lq);
      }
      const bf16x8 a = pack8(v0, v1);
      #pragma unroll
      for (int cc = 0; cc < 2; ++cc) {
        const int cb = 2 * hh + cc;
        const bf16x8 bb = *(const bf16x8*)&t2nf[(kb * 4 + cb) * 512 + ln * 8];
        d[cc] = __builtin_amdgcn_mfma_f32_16x16x32_bf16(a, bb, d[cc], 0, 0, 0);
      }
    }
  }
  #pragma unroll
  for (int cc = 0; cc < 2; ++cc)
    #pragma unroll
    for (int r = 0; r < 4; ++r)
      sH0[rowm + r][16 * (2 * hh + cc) + lr] = (rowm + r < tk) ? d[cc][r] : 0.f;
  __syncthreads();

  // ---- norms -> inverse
  if (tid < 64) {
    float ss = 0.f;
    #pragma unroll
    for (int k = 0; k < 64; ++k) { const float vv = sH0[tid][k]; ss = fmaf(vv, vv, ss); }
    sR[tid] = 1.f / fmaxf(sqrtf(ss), 1e-6f);
  }
  __syncthreads();
  #pragma unroll
  for (int p = 0; p < 8; ++p) {
    const int o = tid + p * 512;
    sU[o >> 6][o & 63] = sH0[o >> 6][o & 63] * sR[o >> 6];
  }
  __syncthreads();

  // ---- A = relu(Hn @ Hn^T), mask, +diag
  #pragma unroll
  for (int cc = 0; cc < 2; ++cc) d[cc] = (f32x4){0.f, 0.f, 0.f, 0.f};
  #pragma unroll
  for (int kb = 0; kb < 2; ++kb) {
    const bf16x8 a = ldsA_frag(sU, g, kb, ln);
    #pragma unroll
    for (int cc = 0; cc < 2; ++cc)
      d[cc] = __builtin_amdgcn_mfma_f32_16x16x32_bf16(a, ldsBT_frag(sU, 2 * hh + cc, kb, ln), d[cc], 0, 0, 0);
  }
  __syncthreads();
  #pragma unroll
  for (int cc = 0; cc < 2; ++cc)
    #pragma unroll
    for (int r = 0; r < 4; ++r) {
      const int row = rowm + r, col = 16 * (2 * hh + cc) + lr;
      float ss = fmaxf(d[cc][r], 0.f);
      ss = (row < tk && col < tk) ? ss : 0.f;
      if (row == col && row < tk) ss += 1.f;
      sA[row][col] = ss;
    }
  __syncthreads();

  // ---- row-normalize A
  if (tid < 64) {
    float rs = 0.f;
    #pragma unroll
    for (int j = 0; j < 64; ++j) rs += sA[tid][j];
    sR[tid] = 1.f / fmaxf(rs, 1e-6f);
  }
  __syncthreads();
  #pragma unroll
  for (int p = 0; p < 8; ++p) {
    const int o = tid + p * 512;
    sA[o >> 6][o & 63] *= sR[o >> 6];
  }
  __syncthreads();

  // ---- T = A @ H0
  #pragma unroll
  for (int cc = 0; cc < 2; ++cc) d[cc] = (f32x4){0.f, 0.f, 0.f, 0.f};
  #pragma unroll
  for (int kb = 0; kb < 2; ++kb) {
    const bf16x8 a = ldsA_frag(sA, g, kb, ln);
    #pragma unroll
    for (int cc = 0; cc < 2; ++cc)
      d[cc] = __builtin_amdgcn_mfma_f32_16x16x32_bf16(a, ldsB_frag(sH0, 2 * hh + cc, kb, ln), d[cc], 0, 0, 0);
  }
  __syncthreads();
  #pragma unroll
  for (int cc = 0; cc < 2; ++cc)
    #pragma unroll
    for (int r = 0; r < 4; ++r) sT[rowm + r][16 * (2 * hh + cc) + lr] = d[cc][r];
  __syncthreads();

  // ---- X1 = relu(T @ g1)
  #pragma unroll
  for (int cc = 0; cc < 2; ++cc) d[cc] = (f32x4){0.f, 0.f, 0.f, 0.f};
  #pragma unroll
  for (int kb = 0; kb < 2; ++kb) {
    const bf16x8 a = ldsA_frag(sT, g, kb, ln);
    #pragma unroll
    for (int cc = 0; cc < 2; ++cc) {
      const bf16x8 bb = *(const bf16x8*)&g1f[(kb * 4 + 2 * hh + cc) * 512 + ln * 8];
      d[cc] = __builtin_amdgcn_mfma_f32_16x16x32_bf16(a, bb, d[cc], 0, 0, 0);
    }
  }
  __syncthreads();
  #pragma unroll
  for (int cc = 0; cc < 2; ++cc)
    #pragma unroll
    for (int r = 0; r < 4; ++r)
      sU[rowm + r][16 * (2 * hh + cc) + lr] = fmaxf(d[cc][r], 0.f);
  __syncthreads();

  // ---- T2 = A @ X1
  #pragma unroll
  for (int cc = 0; cc < 2; ++cc) d[cc] = (f32x4){0.f, 0.f, 0.f, 0.f};
  #pragma unroll
  for (int kb = 0; kb < 2; ++kb) {
    const bf16x8 a = ldsA_frag(sA, g, kb, ln);
    #pragma unroll
    for (int cc = 0; cc < 2; ++cc)
      d[cc] = __builtin_amdgcn_mfma_f32_16x16x32_bf16(a, ldsB_frag(sU, 2 * hh + cc, kb, ln), d[cc], 0, 0, 0);
  }
  __syncthreads();
  #pragma unroll
  for (int cc = 0; cc < 2; ++cc)
    #pragma unroll
    for (int r = 0; r < 4; ++r) sT[rowm + r][16 * (2 * hh + cc) + lr] = d[cc][r];
  __syncthreads();

  // ---- Hg = relu(T2 @ g2) -> HgTf frags + LDS (for W matmul)
  #pragma unroll
  for (int cc = 0; cc < 2; ++cc) d[cc] = (f32x4){0.f, 0.f, 0.f, 0.f};
  #pragma unroll
  for (int kb = 0; kb < 2; ++kb) {
    const bf16x8 a = ldsA_frag(sT, g, kb, ln);
    #pragma unroll
    for (int cc = 0; cc < 2; ++cc) {
      const bf16x8 bb = *(const bf16x8*)&g2f[(kb * 4 + 2 * hh + cc) * 512 + ln * 8];
      d[cc] = __builtin_amdgcn_mfma_f32_16x16x32_bf16(a, bb, d[cc], 0, 0, 0);
    }
  }
  __syncthreads();
  #pragma unroll
  for (int cc = 0; cc < 2; ++cc)
    #pragma unroll
    for (int r = 0; r < 4; ++r) {
      const int node = rowm + r, feat = 16 * (2 * hh + cc) + lr;
      const float hv = fmaxf(d[cc][r], 0.f);
      HgTf[(size_t)b * 4096 + bfrag_idx(feat, node, 4)] = f2bf(hv);
      sU[node][feat] = hv;
    }
  __syncthreads();

  // ---- W = Hg @ n2t: wave group hh covers chk {2hh, 2hh+1}
  for (int chkc = 0; chkc < 2; ++chkc) {
    const int chk = 2 * hh + chkc;
    f32x4 aw[8];
    #pragma unroll
    for (int c8 = 0; c8 < 8; ++c8) aw[c8] = (f32x4){0.f, 0.f, 0.f, 0.f};
    #pragma unroll
    for (int kbf = 0; kbf < 2; ++kbf) {
      const bf16x8 a = ldsA_frag(sU, g, kbf, ln);
      #pragma unroll
      for (int c8 = 0; c8 < 8; ++c8) {
        const bf16x8 bb = *(const bf16x8*)&n2tf[(kbf * 32 + chk * 8 + c8) * 512 + ln * 8];
        aw[c8] = __builtin_amdgcn_mfma_f32_16x16x32_bf16(a, bb, aw[c8], 0, 0, 0);
      }
    }
    #pragma unroll
    for (int c8 = 0; c8 < 8; ++c8)
      #pragma unroll
      for (int r = 0; r < 4; ++r) {
        const int m = 16 * g + 4 * lq + r;
        const int cc2 = (chk * 8 + c8) * 16 + lr;
        Wf[(size_t)b * 32768 + bfrag_idx(m, cc2, 32)] = f2bf(aw[c8][r]);
      }
  }
}

// ---------------------------------------------------------------------------
// k_attn: logits(stash)->softmax->back(attn@W)+residual, float4 epilogue
// ---------------------------------------------------------------------------
__global__ __launch_bounds__(256) void k_attn(
    const float* __restrict__ X, const u16* __restrict__ HgTf,
    const u16* __restrict__ Wf, float* __restrict__ out)
{
  __shared__ __align__(16) u16 sAf[4096];
  __shared__ __align__(16) float sBo[4][16][68];
  const int tid = threadIdx.x;
  const int b = blockIdx.x >> 7;
  const int t0 = (blockIdx.x & 127) << 6;
  const float* Xb = X + (size_t)b * N_ * D_;
  float* Ob = out + (size_t)b * N_ * D_;
  const int wv = tid >> 6, ln = tid & 63;
  const int lq = ln >> 4, lr = ln & 15;
  u16* mySf = &sAf[wv * 1024];
  const u16* stash = (const u16*)(out + (size_t)blockIdx.x * 32768);

  f32x4 accL[4];
  #pragma unroll
  for (int cb = 0; cb < 4; ++cb) accL[cb] = (f32x4){0.f, 0.f, 0.f, 0.f};
  #pragma unroll
  for (int kb = 0; kb < 2; ++kb) {
    const bf16x8 a = *(const bf16x8*)&stash[wv * 1024 + kb * 512 + ln * 8];
    #pragma unroll
    for (int cb = 0; cb < 4; ++cb) {
      const bf16x8 bb = *(const bf16x8*)&HgTf[(size_t)b * 4096 + (kb * 4 + cb) * 512 + ln * 8];
      accL[cb] = __builtin_amdgcn_mfma_f32_16x16x32_bf16(a, bb, accL[cb], 0, 0, 0);
    }
  }
  __syncthreads();

  float attnv[4][4];
  #pragma unroll
  for (int r = 0; r < 4; ++r) {
    const float v0 = accL[0][r], v1 = accL[1][r], v2 = accL[2][r], v3 = accL[3][r];
    float mx = fmaxf(fmaxf(v0, v1), fmaxf(v2, v3));
    mx = fmaxf(mx, __shfl_xor(mx, 1)); mx = fmaxf(mx, __shfl_xor(mx, 2));
    mx = fmaxf(mx, __shfl_xor(mx, 4)); mx = fmaxf(mx, __shfl_xor(mx, 8));
    const float e0 = __expf((v0 - mx) * 0.125f), e1 = __expf((v1 - mx) * 0.125f);
    const float e2 = __expf((v2 - mx) * 0.125f), e3 = __expf((v3 - mx) * 0.125f);
    float sm = (e0 + e1) + (e2 + e3);
    sm += __shfl_xor(sm, 1); sm += __shfl_xor(sm, 2);
    sm += __shfl_xor(sm, 4); sm += __shfl_xor(sm, 8);
    const float inv = 1.f / sm;
    attnv[0][r] = e0 * inv; attnv[1][r] = e1 * inv;
    attnv[2][r] = e2 * inv; attnv[3][r] = e3 * inv;
  }
  #pragma unroll
  for (int cb = 0; cb < 4; ++cb)
    #pragma unroll
    for (int r = 0; r < 4; ++r) {
      const int idx = (cb >> 1) * 512 + (4 * lq + r + 16 * (lr >> 2)) * 8 +
                      (lr & 3) + 4 * (cb & 1);
      mySf[idx] = f2bf(attnv[cb][r]);
    }

  for (int chk = 0; chk < 4; ++chk) {
    float4 xres[8];
    #pragma unroll
    for (int h = 0; h < 2; ++h)
      #pragma unroll
      for (int j = 0; j < 4; ++j)
        xres[h * 4 + j] = *(const float4*)(
            Xb + (size_t)(t0 + 16 * wv + 4 * j + lq) * D_ + chk * 128 + h * 64 + 4 * lr);

    f32x4 accB[8];
    #pragma unroll
    for (int c8 = 0; c8 < 8; ++c8) accB[c8] = (f32x4){0.f, 0.f, 0.f, 0.f};
    #pragma unroll
    for (int kb = 0; kb < 2; ++kb) {
      const bf16x8 a = *(const bf16x8*)&mySf[kb * 512 + ln * 8];
      #pragma unroll
      for (int c8 = 0; c8 < 8; ++c8) {
        const bf16x8 bb = *(const bf16x8*)&Wf[(size_t)b * 32768 + (kb * 32 + chk * 8 + c8) * 512 + ln * 8];
        accB[c8] = __builtin_amdgcn_mfma_f32_16x16x32_bf16(a, bb, accB[c8], 0, 0, 0);
      }
    }
    #pragma unroll
    for (int h = 0; h < 2; ++h) {
      #pragma unroll
      for (int c4 = 0; c4 < 4; ++c4)
        #pragma unroll
        for (int r = 0; r < 4; ++r)
          sBo[wv][4 * lq + r][c4 * 16 + lr] = accB[4 * h + c4][r];
      #pragma unroll
      for (int j = 0; j < 4; ++j) {
        const int rloc = 4 * j + lq;
        float4 vv = *(const float4*)&sBo[wv][rloc][4 * lr];
        const float4 xv = xres[h * 4 + j];
        vv.x += xv.x; vv.y += xv.y; vv.z += xv.z; vv.w += xv.w;
        *(float4*)(Ob + (size_t)(t0 + 16 * wv + rloc) * D_ + chk * 128 + h * 64 + 4 * lr) = vv;
      }
    }
  }
}

// ---------------------------------------------------------------------------
extern "C" void kernel_launch(void* const* d_in, const int* in_sizes, int n_in,
                              void* d_out, int out_size, void* d_ws, size_t ws_size,
                              hipStream_t stream)
{
  (void)in_sizes; (void)n_in; (void)out_size; (void)ws_size;
  const float* X   = (const float*)d_in[0];
  const float* W1  = (const float*)d_in[1];
  const float* b1  = (const float*)d_in[2];
  const float* w2  = (const float*)d_in[3];
  const float* b2  = (const float*)d_in[4];
  const float* t2n = (const float*)d_in[5];
  const float* n2t = (const float*)d_in[6];
  const float* g1  = (const float*)d_in[7];
  const float* g2  = (const float*)d_in[8];
  float* out = (float*)d_out;

  char* ws = (char*)d_ws;
  float* scores = (float*)(ws);                  // 256 KB
  u16* t2nf     = (u16*)(ws + 262144);           // 64 KB
  u16* n2tf     = (u16*)(ws + 327680);           // 64 KB
  u16* W1h      = (u16*)(ws + 393216);           // 64 KB
  u16* W1l      = (u16*)(ws + 458752);           // 64 KB
  u16* HgTf     = (u16*)(ws + 524288);           // 64 KB
  u16* g1f      = (u16*)(ws + 589824);           // 8 KB
  u16* g2f      = (u16*)(ws + 598016);           // 8 KB
  int* top_idx  = (int*)(ws + 606208);           // 2 KB
  int* take_k   = (int*)(ws + 608256);           // 32 B
  u16* Wf       = (u16*)(ws + 609280);           // 512 KB

  k_prep<<<64, 256, 0, stream>>>(t2n, n2t, W1, g1, g2, t2nf, n2tf, W1h, W1l, g1f, g2f);
  k_sp<<<1024, 256, 0, stream>>>(X, W1h, W1l, t2nf, b1, w2, b2, scores, out);
  k_select<<<B_, 1024, 0, stream>>>(scores, top_idx, take_k);
  k_graph<<<B_, 512, 0, stream>>>(X, t2nf, n2tf, g1f, g2f, top_idx, take_k, HgTf, Wf);
  k_attn<<<1024, 256, 0, stream>>>(X, HgTf, Wf, out);
}